// Round 2
// baseline (50.758 us; speedup 1.0000x reference)
//
#include <hip/hip_runtime.h>

#define IMG  512
#define CPT  8              // cols per thread
#define RPT  2              // rows per thread
#define CGRP (IMG / CPT)    // 64 col-groups per row
#define RGRP (IMG / RPT)    // 256 row-pairs per image

// tanh via Pade[7/6] (continued-fraction coefficients, exact rational approx):
//   tanh(x) ~= x*(135135 + 17325u + 378u^2 + u^3) /
//                (135135 + 62370u + 3150u^2 + 28u^3),  u = x^2
// |err| <= 1.6e-4 on |x|<=4.7; for |x|>4.7 the ratio stays >= 1 so the
// med3 clamp to [-1,1] bounds err by 1-tanh(4.7) ~= 1.6e-4. One rcp, no exp.
__device__ __forceinline__ float pade_tanh(float v) {
    float u = v * v;
    float n = fmaf(u, fmaf(u, (u + 378.0f), 17325.0f), 135135.0f);
    float d = fmaf(u, fmaf(u, fmaf(u, 28.0f, 3150.0f), 62370.0f), 135135.0f);
    float q = v * n * __builtin_amdgcn_rcpf(d);
    return __builtin_amdgcn_fmed3f(q, -1.0f, 1.0f);
}

__global__ __launch_bounds__(256) void fused_convtap_kernel(
    const float* __restrict__ x,   // (B,1,512,512)
    const float* __restrict__ W,   // (9,1,3,3)
    const float* __restrict__ Bv,  // (9,)
    float* __restrict__ out)       // (B,1,512,512)
{
    const int tid = blockIdx.x * 256 + threadIdx.x;
    const int xg  = tid & (CGRP - 1);          // 0..63
    const int rg  = tid >> 6;                  // b*RGRP + yp
    const int yp  = rg & (RGRP - 1);           // 0..255
    const int b   = rg >> 8;
    const int y0  = yp * RPT;                  // top output row of this thread
    const int x0  = xg * CPT;

    const int rowbase = b * IMG + y0;
    const float* xr = x + (size_t)rowbase * IMG;

    // Uniform weights/bias (compiler emits scalar loads).
    float w[81];
#pragma unroll
    for (int k = 0; k < 81; ++k) w[k] = W[k];
    float bv[9];
#pragma unroll
    for (int c = 0; c < 9; ++c) bv[c] = Bv[c];

    const bool has_l = (x0 > 0);
    const bool has_r = (x0 < IMG - CPT);

    // Four input rows y0-1 .. y0+2, columns x0-1 .. x0+8 (zero outside).
    float rA[10], rB[10], rC[10], rD[10];

    auto load_row = [&](const float* p, float* r) {
        float4 a = *reinterpret_cast<const float4*>(p + x0);
        float4 c = *reinterpret_cast<const float4*>(p + x0 + 4);
        r[1] = a.x; r[2] = a.y; r[3] = a.z; r[4] = a.w;
        r[5] = c.x; r[6] = c.y; r[7] = c.z; r[8] = c.w;
        r[0] = has_l ? p[x0 - 1] : 0.0f;
        r[9] = has_r ? p[x0 + 8] : 0.0f;
    };
    auto zero_row = [&](float* r) {
#pragma unroll
        for (int k = 0; k < 10; ++k) r[k] = 0.0f;
    };

    if (y0 > 0) load_row(xr - IMG, rA); else zero_row(rA);
    load_row(xr, rB);
    load_row(xr + IMG, rC);                       // y0+1 <= 511 always valid
    if (y0 + 2 < IMG) load_row(xr + 2 * IMG, rD); else zero_row(rD);

    // Compute one output row from its three input rows. All loop indices are
    // compile-time constants after unrolling -> fully register-resident.
    auto compute_row = [&](const float* ra, const float* rb, const float* rc,
                           float* o) {
#pragma unroll
        for (int t = 0; t < CPT; ++t) {
            float acc = 0.0f;
#pragma unroll
            for (int i = 0; i < 3; ++i) {
#pragma unroll
                for (int j = 0; j < 3; ++j) {
                    const int c = 3 * i + j;
                    const float* rj = (j == 0) ? ra : (j == 1) ? rb : rc;
                    float fc = bv[c];
#pragma unroll
                    for (int p = 0; p < 3; ++p) {
                        const float* rp = (p == 0) ? ra : (p == 1) ? rb : rc;
#pragma unroll
                        for (int q = 0; q < 3; ++q)
                            fc = fmaf(rp[t + q], w[c * 9 + p * 3 + q], fc);
                    }
                    acc = fmaf(rj[t + i], pade_tanh(fc), acc);
                }
            }
            o[t] = acc;
        }
    };

    float o0[CPT], o1[CPT];
    compute_row(rA, rB, rC, o0);   // output row y0
    compute_row(rB, rC, rD, o1);   // output row y0+1

    float* orow0 = out + (size_t)rowbase * IMG + x0;
    float* orow1 = orow0 + IMG;
    *reinterpret_cast<float4*>(orow0)     = make_float4(o0[0], o0[1], o0[2], o0[3]);
    *reinterpret_cast<float4*>(orow0 + 4) = make_float4(o0[4], o0[5], o0[6], o0[7]);
    *reinterpret_cast<float4*>(orow1)     = make_float4(o1[0], o1[1], o1[2], o1[3]);
    *reinterpret_cast<float4*>(orow1 + 4) = make_float4(o1[4], o1[5], o1[6], o1[7]);
}

extern "C" void kernel_launch(void* const* d_in, const int* in_sizes, int n_in,
                              void* d_out, int out_size, void* d_ws, size_t ws_size,
                              hipStream_t stream) {
    const float* x  = (const float*)d_in[0];   // (B,1,512,512) f32
    const float* W  = (const float*)d_in[1];   // (9,1,3,3)     f32
    const float* Bv = (const float*)d_in[2];   // (9,)          f32
    float* out = (float*)d_out;

    const int batch   = in_sizes[0] / (IMG * IMG);               // 32
    const int threads = batch * RGRP * CGRP;                     // 524288
    const int block   = 256;
    const int grid    = threads / block;                         // 2048

    fused_convtap_kernel<<<grid, block, 0, stream>>>(x, W, Bv, out);
}

// Round 3
// 42.470 us; speedup vs baseline: 1.1951x; 1.1951x over previous
//
#include <hip/hip_runtime.h>

#define IMG  512
#define CPT  8              // cols per thread (4 float2 pairs)
#define CGRP (IMG / CPT)    // 64 col-groups per row

typedef float v2f __attribute__((ext_vector_type(2)));

// tanh(x) = 1 - 2/(exp(2x)+1), exp via v_exp_f32 (exp2): fold 2*log2e into
// one packed multiply. Saturates correctly at +/-1.
__device__ __forceinline__ v2f tanh2(v2f v) {
    const float C = 2.8853900817779268f;   // 2*log2(e)
    v2f z = v * C;                         // v_pk_mul_f32
    float e0 = __builtin_amdgcn_exp2f(z.x);
    float e1 = __builtin_amdgcn_exp2f(z.y);
    v2f ep1 = {e0, e1};
    ep1 = ep1 + (v2f){1.0f, 1.0f};         // v_pk_add_f32
    v2f r = {__builtin_amdgcn_rcpf(ep1.x), __builtin_amdgcn_rcpf(ep1.y)};
    return __builtin_elementwise_fma((v2f){-2.0f, -2.0f}, r,
                                     (v2f){1.0f, 1.0f});  // v_pk_fma_f32
}

__global__ __launch_bounds__(256) void fused_convtap_kernel(
    const float* __restrict__ x,   // (B,1,512,512)
    const float* __restrict__ W,   // (9,1,3,3)
    const float* __restrict__ Bv,  // (9,)
    float* __restrict__ out)       // (B,1,512,512)
{
    const int tid = blockIdx.x * 256 + threadIdx.x;
    const int xg  = tid & (CGRP - 1);          // 0..63
    const int row = tid >> 6;                  // b*IMG + y
    const int y   = row & (IMG - 1);
    const int x0  = xg * CPT;

    const float* xr = x + (size_t)row * IMG;

    // Uniform weights/bias (kernel-arg pointer + constant idx -> scalar loads)
    float w[81];
#pragma unroll
    for (int k = 0; k < 81; ++k) w[k] = W[k];
    float bv[9];
#pragma unroll
    for (int c = 0; c < 9; ++c) bv[c] = Bv[c];

    const bool has_l = (x0 > 0);
    const bool has_r = (x0 < IMG - CPT);

    // Input rows y-1, y, y+1; columns x0-1 .. x0+8 (zero-padded outside).
    float r0[10], r1[10], r2[10];

    auto load_row = [&](const float* p, float* r) {
        float4 a = *reinterpret_cast<const float4*>(p + x0);
        float4 c = *reinterpret_cast<const float4*>(p + x0 + 4);
        r[1] = a.x; r[2] = a.y; r[3] = a.z; r[4] = a.w;
        r[5] = c.x; r[6] = c.y; r[7] = c.z; r[8] = c.w;
        r[0] = has_l ? p[x0 - 1] : 0.0f;
        r[9] = has_r ? p[x0 + 8] : 0.0f;
    };
    auto zero_row = [&](float* r) {
#pragma unroll
        for (int k = 0; k < 10; ++k) r[k] = 0.0f;
    };

    if (y > 0)       load_row(xr - IMG, r0); else zero_row(r0);
                     load_row(xr,       r1);
    if (y < IMG - 1) load_row(xr + IMG, r2); else zero_row(r2);

    // Sliding float2 pairs per row: pr[s] = (r[s], r[s+1]), s = 0..8.
    // These feed v_pk_fma_f32 with a splat weight operand.
    v2f p0[9], p1[9], p2[9];
#pragma unroll
    for (int s = 0; s < 9; ++s) {
        p0[s] = (v2f){r0[s], r0[s + 1]};
        p1[s] = (v2f){r1[s], r1[s + 1]};
        p2[s] = (v2f){r2[s], r2[s + 1]};
    }

#define PAIR(p, idx) ((p) == 0 ? p0[idx] : (p) == 1 ? p1[idx] : p2[idx])

    v2f o2[4];
#pragma unroll
    for (int tp = 0; tp < 4; ++tp) {           // outputs (2tp, 2tp+1)
        v2f acc = {0.0f, 0.0f};
#pragma unroll
        for (int i = 0; i < 3; ++i) {
#pragma unroll
            for (int j = 0; j < 3; ++j) {
                const int c = 3 * i + j;
                v2f fc = {bv[c], bv[c]};
#pragma unroll
                for (int p = 0; p < 3; ++p) {
#pragma unroll
                    for (int q = 0; q < 3; ++q) {
                        const float wk = w[c * 9 + p * 3 + q];
                        fc = __builtin_elementwise_fma(
                            PAIR(p, 2 * tp + q), (v2f){wk, wk}, fc);
                    }
                }
                acc = __builtin_elementwise_fma(
                    PAIR(j, 2 * tp + i), tanh2(fc), acc);
            }
        }
        o2[tp] = acc;
    }
#undef PAIR

    float* orow = out + (size_t)row * IMG + x0;
    *reinterpret_cast<float4*>(orow)     = make_float4(o2[0].x, o2[0].y,
                                                       o2[1].x, o2[1].y);
    *reinterpret_cast<float4*>(orow + 4) = make_float4(o2[2].x, o2[2].y,
                                                       o2[3].x, o2[3].y);
}

extern "C" void kernel_launch(void* const* d_in, const int* in_sizes, int n_in,
                              void* d_out, int out_size, void* d_ws, size_t ws_size,
                              hipStream_t stream) {
    const float* x  = (const float*)d_in[0];   // (B,1,512,512) f32
    const float* W  = (const float*)d_in[1];   // (9,1,3,3)     f32
    const float* Bv = (const float*)d_in[2];   // (9,)          f32
    float* out = (float*)d_out;

    const int batch   = in_sizes[0] / (IMG * IMG);               // 32
    const int threads = batch * IMG * CGRP;                      // 1,048,576
    const int block   = 256;
    const int grid    = threads / block;                         // 4096

    fused_convtap_kernel<<<grid, block, 0, stream>>>(x, W, Bv, out);
}

// Round 5
// 39.079 us; speedup vs baseline: 1.2989x; 1.0868x over previous
//
#include <hip/hip_runtime.h>
#include <stdint.h>

#define IMG  512
#define CPT  8
#define CGRP (IMG / CPT)    // 64 col-groups per row

typedef float    v2f   __attribute__((ext_vector_type(2)));
typedef _Float16 h2    __attribute__((ext_vector_type(2)));
typedef __fp16   f16x2 __attribute__((ext_vector_type(2)));

#define SCALE 2.8853900817779268f   // 2*log2(e), folded into W and bias

static __device__ __forceinline__ h2 pkrtz(float a, float b) {
    f16x2 t = __builtin_amdgcn_cvt_pkrtz(a, b);   // v_cvt_pkrtz_f16_f32
    return __builtin_bit_cast(h2, t);
}

#if __has_builtin(__builtin_amdgcn_fdot2)
#define FDOT2(a, b, c) __builtin_amdgcn_fdot2((a), (b), (c), false)
#else
static __device__ __forceinline__ float fdot2_sw(h2 a, h2 b, float c) {
    return fmaf((float)a.x, (float)b.x, fmaf((float)a.y, (float)b.y, c));
}
#define FDOT2(a, b, c) fdot2_sw((a), (b), (c))
#endif

// ws layout (dwords): [0..35] u32 half2 weight pairs u[c][k] (scaled);
//                     [36..44] w8[c] f32 (scaled); [45..53] bv[c] f32 (scaled)
__global__ void prepack_kernel(const float* __restrict__ W,
                               const float* __restrict__ B,
                               uint32_t* __restrict__ ws) {
    int c = threadIdx.x;
    if (c < 9) {
        const float* wc = W + c * 9;
#pragma unroll
        for (int k = 0; k < 4; ++k) {
            h2 t = pkrtz(wc[2 * k] * SCALE, wc[2 * k + 1] * SCALE);
            ws[c * 4 + k] = __builtin_bit_cast(uint32_t, t);
        }
        ((float*)ws)[36 + c] = wc[8] * SCALE;
        ((float*)ws)[45 + c] = B[c] * SCALE;
    }
}

__global__ __launch_bounds__(256) void fused_convtap_kernel(
    const float* __restrict__ x,       // (B,1,512,512)
    const uint32_t* __restrict__ wsu,  // prepacked weights
    float* __restrict__ out)           // (B,1,512,512)
{
    const float* w8v = (const float*)(wsu + 36);
    const float* bvv = (const float*)(wsu + 45);

    const int tid = blockIdx.x * 256 + threadIdx.x;
    const int xg  = tid & (CGRP - 1);
    const int row = tid >> 6;            // b*IMG + y
    const int y   = row & (IMG - 1);
    const int x0  = xg * CPT;

    const float* xr = x + (size_t)row * IMG;

    // Uniform prepacked weights -> SGPRs.
    h2 u[9][4];
#pragma unroll
    for (int c = 0; c < 9; ++c)
#pragma unroll
        for (int k = 0; k < 4; ++k)
            u[c][k] = __builtin_bit_cast(h2, wsu[c * 4 + k]);
    float w8[9], bv[9];
#pragma unroll
    for (int c = 0; c < 9; ++c) { w8[c] = w8v[c]; bv[c] = bvv[c]; }

    const bool has_l = (x0 > 0);
    const bool has_r = (x0 < IMG - CPT);

    // Input rows y-1, y, y+1; columns x0-1 .. x0+8 (zero-padded outside).
    float r0[10], r1[10], r2[10];
    auto load_row = [&](const float* p, float* r) {
        float4 a = *reinterpret_cast<const float4*>(p + x0);
        float4 c = *reinterpret_cast<const float4*>(p + x0 + 4);
        r[1] = a.x; r[2] = a.y; r[3] = a.z; r[4] = a.w;
        r[5] = c.x; r[6] = c.y; r[7] = c.z; r[8] = c.w;
        r[0] = has_l ? p[x0 - 1] : 0.0f;
        r[9] = has_r ? p[x0 + 8] : 0.0f;
    };
    auto zero_row = [&](float* r) {
#pragma unroll
        for (int k = 0; k < 10; ++k) r[k] = 0.0f;
    };

    if (y > 0)       load_row(xr - IMG, r0); else zero_row(r0);
                     load_row(xr,       r1);
    if (y < IMG - 1) load_row(xr + IMG, r2); else zero_row(r2);

    float o[CPT];
#pragma unroll
    for (int tp = 0; tp < 4; ++tp) {
        const int t0 = 2 * tp;
        // f16 K-pairs for pixels t0 and t0+1:
        // A=(p0q0,p0q1) B=(p0q2,p1q0) C=(p1q1,p1q2) D=(p2q0,p2q1), lone p2q2 f32
        h2 A0 = pkrtz(r0[t0],     r0[t0 + 1]);
        h2 B0 = pkrtz(r0[t0 + 2], r1[t0]);
        h2 C0 = pkrtz(r1[t0 + 1], r1[t0 + 2]);
        h2 D0 = pkrtz(r2[t0],     r2[t0 + 1]);
        h2 A1 = pkrtz(r0[t0 + 1], r0[t0 + 2]);
        h2 B1 = pkrtz(r0[t0 + 3], r1[t0 + 1]);
        h2 C1 = pkrtz(r1[t0 + 2], r1[t0 + 3]);
        h2 D1 = pkrtz(r2[t0 + 1], r2[t0 + 2]);

        v2f acc = {0.0f, 0.0f};
#pragma unroll
        for (int c = 0; c < 9; ++c) {
            float fx = bv[c], fy = bv[c];
            fx = FDOT2(A0, u[c][0], fx);
            fx = FDOT2(B0, u[c][1], fx);
            fx = FDOT2(C0, u[c][2], fx);
            fx = FDOT2(D0, u[c][3], fx);
            fx = fmaf(r2[t0 + 2], w8[c], fx);
            fy = FDOT2(A1, u[c][0], fy);
            fy = FDOT2(B1, u[c][1], fy);
            fy = FDOT2(C1, u[c][2], fy);
            fy = FDOT2(D1, u[c][3], fy);
            fy = fmaf(r2[t0 + 3], w8[c], fy);

            // tanh(fc) = 1 - 2/(exp2(fc*2log2e)+1); scale pre-folded into W,b.
            v2f e   = { __builtin_amdgcn_exp2f(fx), __builtin_amdgcn_exp2f(fy) };
            v2f ep1 = e + (v2f){1.0f, 1.0f};
            v2f rr  = { __builtin_amdgcn_rcpf(ep1.x), __builtin_amdgcn_rcpf(ep1.y) };
            v2f th  = __builtin_elementwise_fma((v2f){-2.0f, -2.0f}, rr,
                                                (v2f){1.0f, 1.0f});

            // tap stage: out += patch[j][i] * tanh(fc_c), c = 3i+j (f32 path)
            const int i = c / 3, j = c - 3 * i;
            const float* rj = (j == 0) ? r0 : (j == 1) ? r1 : r2;
            v2f px2 = { rj[t0 + i], rj[t0 + 1 + i] };
            acc = __builtin_elementwise_fma(px2, th, acc);
        }
        o[t0] = acc.x; o[t0 + 1] = acc.y;
    }

    float* orow = out + (size_t)row * IMG + x0;
    *reinterpret_cast<float4*>(orow)     = make_float4(o[0], o[1], o[2], o[3]);
    *reinterpret_cast<float4*>(orow + 4) = make_float4(o[4], o[5], o[6], o[7]);
}

extern "C" void kernel_launch(void* const* d_in, const int* in_sizes, int n_in,
                              void* d_out, int out_size, void* d_ws, size_t ws_size,
                              hipStream_t stream) {
    const float* x  = (const float*)d_in[0];   // (B,1,512,512) f32
    const float* W  = (const float*)d_in[1];   // (9,1,3,3)     f32
    const float* Bv = (const float*)d_in[2];   // (9,)          f32
    float* out = (float*)d_out;
    uint32_t* ws = (uint32_t*)d_ws;

    prepack_kernel<<<1, 64, 0, stream>>>(W, Bv, ws);

    const int batch   = in_sizes[0] / (IMG * IMG);   // 32
    const int threads = batch * IMG * CGRP;          // 1,048,576
    const int grid    = threads / 256;               // 4096
    fused_convtap_kernel<<<grid, 256, 0, stream>>>(x, ws, out);
}